// Round 5
// baseline (260.351 us; speedup 1.0000x reference)
//
#include <hip/hip_runtime.h>

// GRU B=32,T=50,N=1024,C=128,H=64 via fp16 MFMA 16x16x32, fp32 accum.
// 512 blocks x 4 waves, 2 blocks/CU -> 2 waves/SIMD. Each wave privately owns
// 16 sequences for all 50 steps: ZERO barriers in the main loop (h lives in a
// wave-private swizzled LDS buffer; same-wave DS ops are ordered).
// Wih fp16 in LDS (swizzled, shared per block); Whh entirely in registers
// (24 B-frags = 96 VGPR); x loaded direct from global with 1-step prefetch.

typedef _Float16 half8 __attribute__((ext_vector_type(8)));
typedef float f32x4 __attribute__((ext_vector_type(4)));

constexpr int T_ = 50, N_ = 1024, C_ = 128, H_ = 64;
constexpr uint32_t WIH_OFF = 0;        // 192 rows x 256B (128 f16) = 49152
constexpr uint32_t HT_OFF  = 49152;    // 4 waves x 16 rows x 128B  =  8192
constexpr int LDS_BYTES = 57344;       // 2 blocks/CU -> 114688 <= 160K

__global__ void prep_weights(const float* __restrict__ Wih, const float* __restrict__ Whh,
                             _Float16* __restrict__ w16) {
  int i = blockIdx.x * 256 + threadIdx.x;
  if (i < 192 * 128) w16[i] = (_Float16)Wih[i];
  if (i < 192 * 64)  w16[24576 + i] = (_Float16)Whh[i];
}

__device__ __forceinline__ float sigm(float x) {
  return __builtin_amdgcn_rcpf(1.f + __expf(-x));
}

__global__ __launch_bounds__(256, 2) void gru_tlp(
    const float* __restrict__ x, const _Float16* __restrict__ w16,
    const float* __restrict__ bih, const float* __restrict__ bhh,
    float* __restrict__ out)
{
  __shared__ __align__(16) char lds[LDS_BYTES];
  const int tid = threadIdx.x;

  // ---- stage Wih into LDS (256B rows, granule ^= row&7); zero h bufs ----
  {
#pragma unroll
    for (int rep = 0; rep < 12; ++rep) {           // 3072 16B chunks
      int i = tid + rep * 256;
      int row = i >> 4;
      uint32_t byte = ((uint32_t)i << 4) ^ ((uint32_t)(row & 7) << 4);
      *(half8*)(lds + WIH_OFF + byte) = *(const half8*)(w16 + i * 8);
    }
    half8 zz = {};
    *(half8*)(lds + HT_OFF + tid * 32)      = zz;  // 256*32 = 8192 B
    *(half8*)(lds + HT_OFF + tid * 32 + 16) = zz;
  }
  __syncthreads();   // the ONLY barrier

  const int wv = tid >> 6, lane = tid & 63;
  const int c = lane & 15, g = lane >> 4;
  const int sw7 = c & 7;
  const uint32_t ht = HT_OFF + (uint32_t)wv * 2048;
  const int seq0 = blockIdx.x * 64 + wv * 16;      // 16 seqs, same batch b
  const int b = seq0 >> 10, n0 = seq0 & (N_ - 1);

  // ---- Whh entirely in registers: B-frag(jt,ks2): row j = jt*16+c, k = ks2*32+g*8 ----
  const _Float16* whh = w16 + 24576;
  half8 wf[12][2];
#pragma unroll
  for (int jt = 0; jt < 12; ++jt)
#pragma unroll
    for (int ks2 = 0; ks2 < 2; ++ks2)
      wf[jt][ks2] = *(const half8*)(whh + (jt * 16 + c) * 64 + ks2 * 32 + g * 8);

  // ---- per-lane biases: hidden j = j4*16 + c ----
  float br[4], bz[4], bin_[4], bhn_[4];
#pragma unroll
  for (int j4 = 0; j4 < 4; ++j4) {
    int j = j4 * 16 + c;
    br[j4]   = bih[j] + bhh[j];
    bz[j4]   = bih[64 + j] + bhh[64 + j];
    bin_[j4] = bih[128 + j];
    bhn_[j4] = bhh[128 + j];
  }

  float hr[16];
#pragma unroll
  for (int i = 0; i < 16; ++i) hr[i] = 0.f;

  // x A-frag: row(seq)=c, k = ks*32 + g*8 + i
  const float* xlane = x + ((size_t)b * T_ * N_ + n0 + c) * C_ + g * 8;
  const size_t stepstride = (size_t)N_ * C_;

  // Wih B-frag: row = jt*16+c (row&7 == c&7), k-chunk ks, granule (ks*4+g)^sw7
#define WIHB(jt, ks) \
  (*(const half8*)(lds + WIH_OFF + (uint32_t)(((jt) * 16 + c) * 256) + \
                   (uint32_t)((((ks) * 4 + g) ^ sw7) << 4)))
#define MFMA16(a, bf, acc) __builtin_amdgcn_mfma_f32_16x16x32_f16((a), (bf), (acc), 0, 0, 0)

  // prologue: load x(t=0)
  float4 raw[8];
#pragma unroll
  for (int ks = 0; ks < 4; ++ks) {
    raw[ks * 2]     = *(const float4*)(xlane + ks * 32);
    raw[ks * 2 + 1] = *(const float4*)(xlane + ks * 32 + 4);
  }

  for (int t = 0; t < T_; ++t) {
    // (1) convert raw -> fp16 A-frags (vmcnt wait lands here)
    half8 xf[4];
#pragma unroll
    for (int ks = 0; ks < 4; ++ks) {
      const float4 lo = raw[ks * 2], hi = raw[ks * 2 + 1];
      half8 v;
      v[0] = (_Float16)lo.x; v[1] = (_Float16)lo.y;
      v[2] = (_Float16)lo.z; v[3] = (_Float16)lo.w;
      v[4] = (_Float16)hi.x; v[5] = (_Float16)hi.y;
      v[6] = (_Float16)hi.z; v[7] = (_Float16)hi.w;
      xf[ks] = v;
    }
    // (2) prefetch x(t+1): in flight across the whole step
    {
      const int tn = (t + 1 < T_) ? t + 1 : T_ - 1;
      const float* xp = xlane + (size_t)tn * stepstride;
#pragma unroll
      for (int ks = 0; ks < 4; ++ks) {
        raw[ks * 2]     = *(const float4*)(xp + ks * 32);
        raw[ks * 2 + 1] = *(const float4*)(xp + ks * 32 + 4);
      }
    }
    // (3) h A-frags early (latency hidden under gi MFMAs)
    half8 ha[2];
#pragma unroll
    for (int ks2 = 0; ks2 < 2; ++ks2)
      ha[ks2] = *(const half8*)(lds + ht + (uint32_t)c * 128 +
                                (uint32_t)(((ks2 * 4 + g) ^ sw7) << 4));

    f32x4 aR[4], aZ[4], aN[4], aH[4];
#pragma unroll
    for (int j4 = 0; j4 < 4; ++j4) {
      aR[j4] = (f32x4){0.f, 0.f, 0.f, 0.f}; aZ[j4] = (f32x4){0.f, 0.f, 0.f, 0.f};
      aN[j4] = (f32x4){0.f, 0.f, 0.f, 0.f}; aH[j4] = (f32x4){0.f, 0.f, 0.f, 0.f};
    }

    // (4) gi = Wih @ x, K=128: 12 independent tiles per ks
#pragma unroll
    for (int ks = 0; ks < 4; ++ks) {
      const half8 a = xf[ks];
#pragma unroll
      for (int j4 = 0; j4 < 4; ++j4) aR[j4] = MFMA16(a, WIHB(j4, ks),     aR[j4]);
#pragma unroll
      for (int j4 = 0; j4 < 4; ++j4) aZ[j4] = MFMA16(a, WIHB(4 + j4, ks), aZ[j4]);
#pragma unroll
      for (int j4 = 0; j4 < 4; ++j4) aN[j4] = MFMA16(a, WIHB(8 + j4, ks), aN[j4]);
    }

    // (5) gh = Whh @ h, K=64: B-frags from registers
#pragma unroll
    for (int ks2 = 0; ks2 < 2; ++ks2) {
      const half8 a = ha[ks2];
#pragma unroll
      for (int j4 = 0; j4 < 4; ++j4) aR[j4] = MFMA16(a, wf[j4][ks2],     aR[j4]);
#pragma unroll
      for (int j4 = 0; j4 < 4; ++j4) aZ[j4] = MFMA16(a, wf[4 + j4][ks2], aZ[j4]);
#pragma unroll
      for (int j4 = 0; j4 < 4; ++j4) aH[j4] = MFMA16(a, wf[8 + j4][ks2], aH[j4]);
    }

    // (6) gates: lane holds D(seq = g*4+v, j = j4*16+c); h carry fp32 in regs
#pragma unroll
    for (int j4 = 0; j4 < 4; ++j4) {
#pragma unroll
      for (int v = 0; v < 4; ++v) {
        const float r = sigm(aR[j4][v] + br[j4]);
        const float z = sigm(aZ[j4][v] + bz[j4]);
        const float np = aN[j4][v] + bin_[j4] + r * (aH[j4][v] + bhn_[j4]);
        const float nn = 1.f - 2.f * __builtin_amdgcn_rcpf(__expf(2.f * np) + 1.f);
        const float hn = (1.f - z) * nn + z * hr[j4 * 4 + v];
        hr[j4 * 4 + v] = hn;
        const int seq = g * 4 + v;
        const uint32_t gr = (uint32_t)((j4 * 2 + (c >> 3)) ^ (seq & 7));
        const uint32_t byte = ht + (uint32_t)seq * 128 + (gr << 4) + (uint32_t)((c & 7) * 2);
        *(_Float16*)(lds + byte) = (_Float16)hn;   // wave-private; DS in-order
      }
    }
  }

  // ---- store final h (fp32 carry) ----
#pragma unroll
  for (int j4 = 0; j4 < 4; ++j4)
#pragma unroll
    for (int v = 0; v < 4; ++v)
      out[(size_t)(seq0 + g * 4 + v) * H_ + j4 * 16 + c] = hr[j4 * 4 + v];
#undef WIHB
#undef MFMA16
}

extern "C" void kernel_launch(void* const* d_in, const int* in_sizes, int n_in,
                              void* d_out, int out_size, void* d_ws, size_t ws_size,
                              hipStream_t stream) {
  const float* chars = (const float*)d_in[0];
  const float* Wih   = (const float*)d_in[1];
  const float* Whh   = (const float*)d_in[2];
  const float* bih   = (const float*)d_in[3];
  const float* bhh   = (const float*)d_in[4];

  _Float16* w16 = (_Float16*)d_ws;   // 36864 f16 = 73728 B

  prep_weights<<<96, 256, 0, stream>>>(Wih, Whh, w16);
  gru_tlp<<<512, 256, 0, stream>>>(chars, w16, bih, bhh, (float*)d_out);
}

// Round 6
// 224.652 us; speedup vs baseline: 1.1589x; 1.1589x over previous
//
#include <hip/hip_runtime.h>

// GRU B=32,T=50,N=1024,C=128,H=64 via fp16 MFMA 16x16x32, fp32 accum.
// 512 blocks x 4 waves, 2 blocks/CU -> 2 waves/SIMD. Each wave privately owns
// 16 sequences for all 50 steps: ZERO barriers in the main loop.
// Register-budget discipline (R5 spilled at ~270 regs):
//   - phase-split over 4 hidden-col tiles -> accum 16 VGPR (was 64)
//   - Whh in registers (96), Wih in block-shared LDS (swizzled)
//   - peak ~220 VGPR < 256 cap at 2 waves/SIMD.

typedef _Float16 half8 __attribute__((ext_vector_type(8)));
typedef float f32x4 __attribute__((ext_vector_type(4)));

constexpr int T_ = 50, N_ = 1024, C_ = 128, H_ = 64;
constexpr uint32_t WIH_OFF = 0;        // 192 rows x 256B (128 f16) = 49152
constexpr uint32_t HT_OFF  = 49152;    // 4 waves x 16 rows x 128B  =  8192
constexpr int LDS_BYTES = 57344;       // x2 blocks/CU = 114688 <= 160K

__global__ void prep_weights(const float* __restrict__ Wih, const float* __restrict__ Whh,
                             _Float16* __restrict__ w16) {
  int i = blockIdx.x * 256 + threadIdx.x;
  if (i < 192 * 128) w16[i] = (_Float16)Wih[i];
  if (i < 192 * 64)  w16[24576 + i] = (_Float16)Whh[i];
}

__device__ __forceinline__ float sigm(float x) {
  return __builtin_amdgcn_rcpf(1.f + __expf(-x));
}

__global__ __launch_bounds__(256, 2) void gru_phase(
    const float* __restrict__ x, const _Float16* __restrict__ w16,
    const float* __restrict__ bih, const float* __restrict__ bhh,
    float* __restrict__ out)
{
  __shared__ __align__(16) char lds[LDS_BYTES];
  const int tid = threadIdx.x;

  // ---- stage Wih into LDS (256B rows, granule ^= row&7); zero h bufs ----
  {
#pragma unroll
    for (int rep = 0; rep < 12; ++rep) {           // 3072 16B chunks
      int i = tid + rep * 256;
      int row = i >> 4;
      uint32_t byte = ((uint32_t)i << 4) ^ ((uint32_t)(row & 7) << 4);
      *(half8*)(lds + WIH_OFF + byte) = *(const half8*)(w16 + i * 8);
    }
    half8 zz = {};
    *(half8*)(lds + HT_OFF + tid * 32)      = zz;
    *(half8*)(lds + HT_OFF + tid * 32 + 16) = zz;
  }
  __syncthreads();   // the ONLY barrier

  const int wv = tid >> 6, lane = tid & 63;
  const int c = lane & 15, g = lane >> 4;
  const int sw7 = c & 7;
  const uint32_t ht = HT_OFF + (uint32_t)wv * 2048;
  const int seq0 = blockIdx.x * 64 + wv * 16;
  const int b = seq0 >> 10, n0 = seq0 & (N_ - 1);

  // ---- Whh in registers: wf[gate][jt][ks2], row j = gate*64+jt*16+c ----
  const _Float16* whh = w16 + 24576;
  half8 wf[3][4][2];
#pragma unroll
  for (int gate = 0; gate < 3; ++gate)
#pragma unroll
    for (int jt = 0; jt < 4; ++jt)
#pragma unroll
      for (int ks2 = 0; ks2 < 2; ++ks2)
        wf[gate][jt][ks2] =
            *(const half8*)(whh + (gate * 64 + jt * 16 + c) * 64 + ks2 * 32 + g * 8);

  // ---- per-lane biases: hidden j = jt*16 + c ----
  float br[4], bz[4], bin_[4], bhn_[4];
#pragma unroll
  for (int jt = 0; jt < 4; ++jt) {
    int j = jt * 16 + c;
    br[jt]   = bih[j] + bhh[j];
    bz[jt]   = bih[64 + j] + bhh[64 + j];
    bin_[jt] = bih[128 + j];
    bhn_[jt] = bhh[128 + j];
  }

  float hr[16];
#pragma unroll
  for (int i = 0; i < 16; ++i) hr[i] = 0.f;

  const float* xlane = x + ((size_t)b * T_ * N_ + n0 + c) * C_ + g * 8;
  const size_t stepstride = (size_t)N_ * C_;

#define WIHB(gate, jt, ks) \
  (*(const half8*)(lds + WIH_OFF + (uint32_t)((((gate) * 64 + (jt) * 16 + c)) * 256) + \
                   (uint32_t)((((ks) * 4 + g) ^ sw7) << 4)))
#define MFMA16(a, bf, acc) __builtin_amdgcn_mfma_f32_16x16x32_f16((a), (bf), (acc), 0, 0, 0)

  // prologue: load x(t=0)
  float4 raw[8];
#pragma unroll
  for (int ks = 0; ks < 4; ++ks) {
    raw[ks * 2]     = *(const float4*)(xlane + ks * 32);
    raw[ks * 2 + 1] = *(const float4*)(xlane + ks * 32 + 4);
  }

  for (int t = 0; t < T_; ++t) {
    // (1) convert raw -> fp16 A-frags (vmcnt wait lands here)
    half8 xf[4];
#pragma unroll
    for (int ks = 0; ks < 4; ++ks) {
      const float4 lo = raw[ks * 2], hi = raw[ks * 2 + 1];
      half8 v;
      v[0] = (_Float16)lo.x; v[1] = (_Float16)lo.y;
      v[2] = (_Float16)lo.z; v[3] = (_Float16)lo.w;
      v[4] = (_Float16)hi.x; v[5] = (_Float16)hi.y;
      v[6] = (_Float16)hi.z; v[7] = (_Float16)hi.w;
      xf[ks] = v;
    }
    // (2) prefetch x(t+1): in flight for the entire step
    {
      const int tn = (t + 1 < T_) ? t + 1 : T_ - 1;
      const float* xp = xlane + (size_t)tn * stepstride;
#pragma unroll
      for (int ks = 0; ks < 4; ++ks) {
        raw[ks * 2]     = *(const float4*)(xp + ks * 32);
        raw[ks * 2 + 1] = *(const float4*)(xp + ks * 32 + 4);
      }
    }
    // (3) h A-frags
    half8 ha[2];
#pragma unroll
    for (int ks2 = 0; ks2 < 2; ++ks2)
      ha[ks2] = *(const half8*)(lds + ht + (uint32_t)c * 128 +
                                (uint32_t)(((ks2 * 4 + g) ^ sw7) << 4));

    // (4) four col-tile phases; accum lives only within a phase (16 VGPR)
#pragma unroll
    for (int jt = 0; jt < 4; ++jt) {
      f32x4 aR = {0.f, 0.f, 0.f, 0.f}, aZ = {0.f, 0.f, 0.f, 0.f};
      f32x4 aN = {0.f, 0.f, 0.f, 0.f}, aH = {0.f, 0.f, 0.f, 0.f};
#pragma unroll
      for (int ks = 0; ks < 4; ++ks) {
        const half8 a = xf[ks];
        aR = MFMA16(a, WIHB(0, jt, ks), aR);
        aZ = MFMA16(a, WIHB(1, jt, ks), aZ);
        aN = MFMA16(a, WIHB(2, jt, ks), aN);
      }
#pragma unroll
      for (int ks2 = 0; ks2 < 2; ++ks2) {
        const half8 a = ha[ks2];
        aR = MFMA16(a, wf[0][jt][ks2], aR);
        aZ = MFMA16(a, wf[1][jt][ks2], aZ);
        aH = MFMA16(a, wf[2][jt][ks2], aH);
      }
      // gates for this col tile: lane holds D(seq = g*4+v, j = jt*16+c)
#pragma unroll
      for (int v = 0; v < 4; ++v) {
        const float r = sigm(aR[v] + br[jt]);
        const float z = sigm(aZ[v] + bz[jt]);
        const float np = aN[v] + bin_[jt] + r * (aH[v] + bhn_[jt]);
        const float nn = 1.f - 2.f * __builtin_amdgcn_rcpf(__expf(2.f * np) + 1.f);
        const float hn = (1.f - z) * nn + z * hr[jt * 4 + v];
        hr[jt * 4 + v] = hn;
        const int seq = g * 4 + v;
        const uint32_t gr = (uint32_t)((jt * 2 + (c >> 3)) ^ (seq & 7));
        const uint32_t byte = ht + (uint32_t)seq * 128 + (gr << 4) + (uint32_t)((c & 7) * 2);
        *(_Float16*)(lds + byte) = (_Float16)hn;   // wave-private; DS in-order
      }
    }
  }

  // ---- store final h (fp32 carry) ----
#pragma unroll
  for (int jt = 0; jt < 4; ++jt)
#pragma unroll
    for (int v = 0; v < 4; ++v)
      out[(size_t)(seq0 + g * 4 + v) * H_ + jt * 16 + c] = hr[jt * 4 + v];
#undef WIHB
#undef MFMA16
}

extern "C" void kernel_launch(void* const* d_in, const int* in_sizes, int n_in,
                              void* d_out, int out_size, void* d_ws, size_t ws_size,
                              hipStream_t stream) {
  const float* chars = (const float*)d_in[0];
  const float* Wih   = (const float*)d_in[1];
  const float* Whh   = (const float*)d_in[2];
  const float* bih   = (const float*)d_in[3];
  const float* bhh   = (const float*)d_in[4];

  _Float16* w16 = (_Float16*)d_ws;   // 36864 f16 = 73728 B

  prep_weights<<<96, 256, 0, stream>>>(Wih, Whh, w16);
  gru_phase<<<512, 256, 0, stream>>>(chars, w16, bih, bhh, (float*)d_out);
}

// Round 7
// 216.164 us; speedup vs baseline: 1.2044x; 1.0393x over previous
//
#include <hip/hip_runtime.h>

// GRU B=32,T=50,N=1024,C=128,H=64 via fp16 MFMA 16x16x32, fp32 accum.
// R7: occupancy via independent small blocks. 2048 blocks x 256 thr (4 waves).
// Each block owns 16 sequences; wave jt in {0..3} computes hidden cols
// jt*16..jt*16+15. VGPR <= 128 (launch_bounds(256,4)) + 36 KB LDS
// -> 4 blocks/CU -> each SIMD runs 4 waves from 4 INDEPENDENT blocks
// (barrier stalls decorrelated). One __syncthreads per step.
//   - Wih quarter (48 rows) in REGISTERS per wave (12 half8 frags)
//   - Whh in block-shared LDS (24 KB, swizzled)
//   - x staged once/block into LDS f16 (4 KB dbuf), 1-step reg prefetch
//   - h double-buffered 2x2 KB LDS f16 + fp32 carry in regs

typedef _Float16 half8 __attribute__((ext_vector_type(8)));
typedef float f32x4 __attribute__((ext_vector_type(4)));

constexpr int T_ = 50, N_ = 1024, C_ = 128, H_ = 64;
constexpr uint32_t WHH_OFF = 0;       // 192 rows x 128B = 24576
constexpr uint32_t XB_OFF  = 24576;   // 2 x 4096 (16 seq x 128 f16) = 8192
constexpr uint32_t HB_OFF  = 32768;   // 2 x 2048 (16 seq x 64 f16)  = 4096
constexpr int LDS_BYTES = 36864;      // x4 blocks/CU = 147456 <= 160K

__global__ void prep_weights(const float* __restrict__ Wih, const float* __restrict__ Whh,
                             _Float16* __restrict__ w16) {
  int i = blockIdx.x * 256 + threadIdx.x;
  if (i < 192 * 128) w16[i] = (_Float16)Wih[i];
  if (i < 192 * 64)  w16[24576 + i] = (_Float16)Whh[i];
}

__device__ __forceinline__ float sigm(float x) {
  return __builtin_amdgcn_rcpf(1.f + __expf(-x));
}

__device__ __forceinline__ half8 cvt8(float4 lo, float4 hi) {
  half8 v;
  v[0] = (_Float16)lo.x; v[1] = (_Float16)lo.y;
  v[2] = (_Float16)lo.z; v[3] = (_Float16)lo.w;
  v[4] = (_Float16)hi.x; v[5] = (_Float16)hi.y;
  v[6] = (_Float16)hi.z; v[7] = (_Float16)hi.w;
  return v;
}

__global__ __launch_bounds__(256, 4) void gru_g4(
    const float* __restrict__ x, const _Float16* __restrict__ w16,
    const float* __restrict__ bih, const float* __restrict__ bhh,
    float* __restrict__ out)
{
  __shared__ __align__(16) char lds[LDS_BYTES];
  const int tid = threadIdx.x;
  const int wv = tid >> 6, lane = tid & 63;
  const int c = lane & 15, g = lane >> 4;
  const int jt = wv;                               // this wave's col tile
  const int seq0 = blockIdx.x * 16;
  const int b = seq0 >> 10, n0 = seq0 & (N_ - 1);

  // ---- stage Whh into LDS (128B rows, granule ^= row&7); zero h bufs ----
  {
    const _Float16* whh = w16 + 24576;
#pragma unroll
    for (int rep = 0; rep < 6; ++rep) {            // 1536 16B chunks
      int i = tid + rep * 256;
      int row = i >> 3, gr = i & 7;
      uint32_t byte = (uint32_t)row * 128 + (uint32_t)((gr ^ (row & 7)) << 4);
      *(half8*)(lds + WHH_OFF + byte) = *(const half8*)(whh + i * 8);
    }
    half8 zz = {};
    *(half8*)(lds + HB_OFF + tid * 16) = zz;       // 4096 B both h bufs
  }

  // ---- Wih quarter in registers: wr[gate][ks], row = gate*64 + jt*16 + c ----
  half8 wr[3][4];
#pragma unroll
  for (int gate = 0; gate < 3; ++gate)
#pragma unroll
    for (int ks = 0; ks < 4; ++ks)
      wr[gate][ks] = *(const half8*)(w16 + (gate * 64 + jt * 16 + c) * 128 + ks * 32 + g * 8);

  // ---- per-lane biases for hidden col j = jt*16 + c ----
  const int j = jt * 16 + c;
  const float br   = bih[j] + bhh[j];
  const float bz   = bih[64 + j] + bhh[64 + j];
  const float bin_ = bih[128 + j];
  const float bhn_ = bhh[128 + j];

  float hr[4] = {0.f, 0.f, 0.f, 0.f};             // h carry for seq = g*4+v

  // ---- x staging mapping: thread -> (seq = tid>>4, ch0 = (tid&15)*8) ----
  const int sseq = tid >> 4;
  const uint32_t xw_off = (uint32_t)sseq * 256 +
                          (uint32_t)(((tid & 15) ^ (sseq & 7)) << 4);
  const float* xbase = x + ((size_t)b * T_ * N_ + n0 + sseq) * C_ + (tid & 15) * 8;
  const size_t stepstride = (size_t)N_ * C_;

#define WHHB(gate, ks2) \
  (*(const half8*)(lds + WHH_OFF + (uint32_t)(((gate) * 64 + jt * 16 + c) * 128) + \
                   (uint32_t)((((ks2) * 4 + g) ^ (c & 7)) << 4)))
#define MFMA16(a, bf, acc) __builtin_amdgcn_mfma_f32_16x16x32_f16((a), (bf), (acc), 0, 0, 0)

  // ---- prologue: stage x(0) into xbuf[0]; issue raw loads for x(1) ----
  {
    float4 r0 = *(const float4*)(xbase);
    float4 r1 = *(const float4*)(xbase + 4);
    *(half8*)(lds + XB_OFF + xw_off) = cvt8(r0, r1);
  }
  float4 ra = *(const float4*)(xbase + stepstride);
  float4 rb = *(const float4*)(xbase + stepstride + 4);
  __syncthreads();

  for (int t = 0; t < T_; ++t) {
    const uint32_t xr  = XB_OFF + (uint32_t)(t & 1) * 4096;
    const uint32_t hrd = HB_OFF + (uint32_t)((t + 1) & 1) * 2048;
    const uint32_t hwr = HB_OFF + (uint32_t)(t & 1) * 2048;

    // A-frags from LDS: x row = c (16 granules), h row = c (8 granules)
    half8 xa[4];
#pragma unroll
    for (int ks = 0; ks < 4; ++ks)
      xa[ks] = *(const half8*)(lds + xr + (uint32_t)c * 256 +
                               (uint32_t)(((ks * 4 + g) ^ (c & 7)) << 4));
    half8 ha[2];
#pragma unroll
    for (int ks2 = 0; ks2 < 2; ++ks2)
      ha[ks2] = *(const half8*)(lds + hrd + (uint32_t)c * 128 +
                                (uint32_t)(((ks2 * 4 + g) ^ (c & 7)) << 4));

    f32x4 aR = {0.f, 0.f, 0.f, 0.f}, aZ = {0.f, 0.f, 0.f, 0.f};
    f32x4 aN = {0.f, 0.f, 0.f, 0.f}, aH = {0.f, 0.f, 0.f, 0.f};

    // gi part (K=128, Wih from registers)
#pragma unroll
    for (int ks = 0; ks < 4; ++ks) {
      aR = MFMA16(xa[ks], wr[0][ks], aR);
      aZ = MFMA16(xa[ks], wr[1][ks], aZ);
      aN = MFMA16(xa[ks], wr[2][ks], aN);
    }
    // gh part (K=64, Whh from LDS)
#pragma unroll
    for (int ks2 = 0; ks2 < 2; ++ks2) {
      aR = MFMA16(ha[ks2], WHHB(0, ks2), aR);
      aZ = MFMA16(ha[ks2], WHHB(1, ks2), aZ);
      aH = MFMA16(ha[ks2], WHHB(2, ks2), aH);
    }

    // gates: lane holds D(seq = g*4+v, col j); write h(t) to hbuf[t&1]
#pragma unroll
    for (int v = 0; v < 4; ++v) {
      const float r = sigm(aR[v] + br);
      const float z = sigm(aZ[v] + bz);
      const float np = aN[v] + bin_ + r * (aH[v] + bhn_);
      const float nn = 1.f - 2.f * __builtin_amdgcn_rcpf(__expf(2.f * np) + 1.f);
      const float hn = (1.f - z) * nn + z * hr[v];
      hr[v] = hn;
      const int seq = g * 4 + v;
      const uint32_t gr = (uint32_t)((jt * 2 + (c >> 3)) ^ (seq & 7));
      *(_Float16*)(lds + hwr + (uint32_t)seq * 128 + (gr << 4) +
                   (uint32_t)((c & 7) * 2)) = (_Float16)hn;
    }

    // stage x(t+1) into xbuf[(t+1)&1]; issue raw loads for x(t+2)
    if (t + 1 < T_) {
      *(half8*)(lds + XB_OFF + (uint32_t)((t + 1) & 1) * 4096 + xw_off) = cvt8(ra, rb);
      const int tn2 = (t + 2 < T_) ? t + 2 : T_ - 1;
      const float* xp = xbase + (size_t)tn2 * stepstride;
      ra = *(const float4*)(xp);
      rb = *(const float4*)(xp + 4);
    }
    __syncthreads();
  }

  // ---- store final h (fp32 carry) ----
#pragma unroll
  for (int v = 0; v < 4; ++v)
    out[(size_t)(seq0 + g * 4 + v) * H_ + j] = hr[v];
#undef WHHB
#undef MFMA16
}

extern "C" void kernel_launch(void* const* d_in, const int* in_sizes, int n_in,
                              void* d_out, int out_size, void* d_ws, size_t ws_size,
                              hipStream_t stream) {
  const float* chars = (const float*)d_in[0];
  const float* Wih   = (const float*)d_in[1];
  const float* Whh   = (const float*)d_in[2];
  const float* bih   = (const float*)d_in[3];
  const float* bhh   = (const float*)d_in[4];

  _Float16* w16 = (_Float16*)d_ws;   // 36864 f16 = 73728 B

  prep_weights<<<96, 256, 0, stream>>>(Wih, Whh, w16);
  gru_g4<<<2048, 256, 0, stream>>>(chars, w16, bih, bhh, (float*)d_out);
}

// Round 8
// 207.933 us; speedup vs baseline: 1.2521x; 1.0396x over previous
//
#include <hip/hip_runtime.h>

// GRU B=32,T=50,N=1024,C=128,H=64 via fp16 MFMA 16x16x32, fp32 accum.
// R8 = R6 (zero-barrier, wave-private 16 seqs, phase-split accum, Whh in regs,
// Wih in swizzled LDS) + DEPTH-2 ping-pong x prefetch (rawA/rawB):
// the generation consumed at step t was issued at step t-2 (~2 steps = ~5 us
// earlier), past the ~3.5 us all-CU burst-return time -> no vmcnt stall.
// 512 blocks x 4 waves, 2 blocks/CU, 2 waves/SIMD, ~245 VGPR.

typedef _Float16 half8 __attribute__((ext_vector_type(8)));
typedef float f32x4 __attribute__((ext_vector_type(4)));

constexpr int T_ = 50, N_ = 1024, C_ = 128, H_ = 64;
constexpr uint32_t WIH_OFF = 0;        // 192 rows x 256B (128 f16) = 49152
constexpr uint32_t HT_OFF  = 49152;    // 4 waves x 16 rows x 128B  =  8192
constexpr int LDS_BYTES = 57344;       // x2 blocks/CU = 114688 <= 160K

__global__ void prep_weights(const float* __restrict__ Wih, const float* __restrict__ Whh,
                             _Float16* __restrict__ w16) {
  int i = blockIdx.x * 256 + threadIdx.x;
  if (i < 192 * 128) w16[i] = (_Float16)Wih[i];
  if (i < 192 * 64)  w16[24576 + i] = (_Float16)Whh[i];
}

__device__ __forceinline__ float sigm(float x) {
  return __builtin_amdgcn_rcpf(1.f + __expf(-x));
}

__device__ __forceinline__ half8 cvt8(float4 lo, float4 hi) {
  half8 v;
  v[0] = (_Float16)lo.x; v[1] = (_Float16)lo.y;
  v[2] = (_Float16)lo.z; v[3] = (_Float16)lo.w;
  v[4] = (_Float16)hi.x; v[5] = (_Float16)hi.y;
  v[6] = (_Float16)hi.z; v[7] = (_Float16)hi.w;
  return v;
}

__global__ __launch_bounds__(256, 2) void gru_d2(
    const float* __restrict__ x, const _Float16* __restrict__ w16,
    const float* __restrict__ bih, const float* __restrict__ bhh,
    float* __restrict__ out)
{
  __shared__ __align__(16) char lds[LDS_BYTES];
  const int tid = threadIdx.x;

  // ---- stage Wih into LDS (256B rows, granule ^= row&7); zero h bufs ----
  {
#pragma unroll
    for (int rep = 0; rep < 12; ++rep) {           // 3072 16B chunks
      int i = tid + rep * 256;
      int row = i >> 4;
      uint32_t byte = ((uint32_t)i << 4) ^ ((uint32_t)(row & 7) << 4);
      *(half8*)(lds + WIH_OFF + byte) = *(const half8*)(w16 + i * 8);
    }
    half8 zz = {};
    *(half8*)(lds + HT_OFF + tid * 32)      = zz;
    *(half8*)(lds + HT_OFF + tid * 32 + 16) = zz;
  }
  __syncthreads();   // the ONLY barrier

  const int wv = tid >> 6, lane = tid & 63;
  const int c = lane & 15, g = lane >> 4;
  const int sw7 = c & 7;
  const uint32_t ht = HT_OFF + (uint32_t)wv * 2048;
  const int seq0 = blockIdx.x * 64 + wv * 16;
  const int b = seq0 >> 10, n0 = seq0 & (N_ - 1);

  // ---- Whh in registers: wf[gate][jt][ks2], row j = gate*64+jt*16+c ----
  const _Float16* whh = w16 + 24576;
  half8 wf[3][4][2];
#pragma unroll
  for (int gate = 0; gate < 3; ++gate)
#pragma unroll
    for (int jt = 0; jt < 4; ++jt)
#pragma unroll
      for (int ks2 = 0; ks2 < 2; ++ks2)
        wf[gate][jt][ks2] =
            *(const half8*)(whh + (gate * 64 + jt * 16 + c) * 64 + ks2 * 32 + g * 8);

  // ---- per-lane biases: hidden j = jt*16 + c ----
  float br[4], bz[4], bin_[4], bhn_[4];
#pragma unroll
  for (int jt = 0; jt < 4; ++jt) {
    int j = jt * 16 + c;
    br[jt]   = bih[j] + bhh[j];
    bz[jt]   = bih[64 + j] + bhh[64 + j];
    bin_[jt] = bih[128 + j];
    bhn_[jt] = bhh[128 + j];
  }

  float hr[16];
#pragma unroll
  for (int i = 0; i < 16; ++i) hr[i] = 0.f;

  const float* xlane = x + ((size_t)b * T_ * N_ + n0 + c) * C_ + g * 8;
  const size_t stepstride = (size_t)N_ * C_;

#define WIHB(gate, jt, ks) \
  (*(const half8*)(lds + WIH_OFF + (uint32_t)((((gate) * 64 + (jt) * 16 + c)) * 256) + \
                   (uint32_t)((((ks) * 4 + g) ^ sw7) << 4)))
#define MFMA16(a, bf, acc) __builtin_amdgcn_mfma_f32_16x16x32_f16((a), (bf), (acc), 0, 0, 0)

  // ---- prologue: depth-2 ping-pong — rawA <- x(0), rawB <- x(1) ----
  float4 rawA[8], rawB[8];
#pragma unroll
  for (int ks = 0; ks < 4; ++ks) {
    rawA[ks * 2]     = *(const float4*)(xlane + ks * 32);
    rawA[ks * 2 + 1] = *(const float4*)(xlane + ks * 32 + 4);
  }
#pragma unroll
  for (int ks = 0; ks < 4; ++ks) {
    rawB[ks * 2]     = *(const float4*)(xlane + stepstride + ks * 32);
    rawB[ks * 2 + 1] = *(const float4*)(xlane + stepstride + ks * 32 + 4);
  }

  // One GRU step consuming RAW (x(tcur)), then reloading RAW with x(tcur+2).
#define GRU_STEP(tcur, raw)                                                      \
  do {                                                                           \
    half8 ha[2];                                                                 \
    _Pragma("unroll")                                                            \
    for (int ks2 = 0; ks2 < 2; ++ks2)                                            \
      ha[ks2] = *(const half8*)(lds + ht + (uint32_t)c * 128 +                   \
                                (uint32_t)(((ks2 * 4 + g) ^ sw7) << 4));         \
    half8 xf[4];                                                                 \
    _Pragma("unroll")                                                            \
    for (int ks = 0; ks < 4; ++ks) xf[ks] = cvt8(raw[ks * 2], raw[ks * 2 + 1]);  \
    {                                                                            \
      const int tn = ((tcur) + 2 < T_) ? (tcur) + 2 : T_ - 1;                    \
      const float* xp = xlane + (size_t)tn * stepstride;                         \
      _Pragma("unroll")                                                          \
      for (int ks = 0; ks < 4; ++ks) {                                           \
        raw[ks * 2]     = *(const float4*)(xp + ks * 32);                        \
        raw[ks * 2 + 1] = *(const float4*)(xp + ks * 32 + 4);                    \
      }                                                                          \
    }                                                                            \
    _Pragma("unroll")                                                            \
    for (int jt = 0; jt < 4; ++jt) {                                             \
      f32x4 aR = {0.f, 0.f, 0.f, 0.f}, aZ = {0.f, 0.f, 0.f, 0.f};                \
      f32x4 aN = {0.f, 0.f, 0.f, 0.f}, aH = {0.f, 0.f, 0.f, 0.f};                \
      _Pragma("unroll")                                                          \
      for (int ks = 0; ks < 4; ++ks) {                                           \
        const half8 a = xf[ks];                                                  \
        aR = MFMA16(a, WIHB(0, jt, ks), aR);                                     \
        aZ = MFMA16(a, WIHB(1, jt, ks), aZ);                                     \
        aN = MFMA16(a, WIHB(2, jt, ks), aN);                                     \
      }                                                                          \
      _Pragma("unroll")                                                          \
      for (int ks2 = 0; ks2 < 2; ++ks2) {                                        \
        const half8 a = ha[ks2];                                                 \
        aR = MFMA16(a, wf[0][jt][ks2], aR);                                      \
        aZ = MFMA16(a, wf[1][jt][ks2], aZ);                                      \
        aH = MFMA16(a, wf[2][jt][ks2], aH);                                      \
      }                                                                          \
      _Pragma("unroll")                                                          \
      for (int v = 0; v < 4; ++v) {                                              \
        const float r = sigm(aR[v] + br[jt]);                                    \
        const float z = sigm(aZ[v] + bz[jt]);                                    \
        const float np = aN[v] + bin_[jt] + r * (aH[v] + bhn_[jt]);              \
        const float nn = 1.f - 2.f * __builtin_amdgcn_rcpf(__expf(2.f * np) + 1.f); \
        const float hn = (1.f - z) * nn + z * hr[jt * 4 + v];                    \
        hr[jt * 4 + v] = hn;                                                     \
        const int seq = g * 4 + v;                                               \
        const uint32_t gr = (uint32_t)((jt * 2 + (c >> 3)) ^ (seq & 7));         \
        const uint32_t byte = ht + (uint32_t)seq * 128 + (gr << 4) +             \
                              (uint32_t)((c & 7) * 2);                           \
        *(_Float16*)(lds + byte) = (_Float16)hn;                                 \
      }                                                                          \
    }                                                                            \
  } while (0)

  for (int t = 0; t < T_; t += 2) {
    GRU_STEP(t, rawA);
    GRU_STEP(t + 1, rawB);
  }

  // ---- store final h (fp32 carry) ----
#pragma unroll
  for (int jt = 0; jt < 4; ++jt)
#pragma unroll
    for (int v = 0; v < 4; ++v)
      out[(size_t)(seq0 + g * 4 + v) * H_ + jt * 16 + c] = hr[jt * 4 + v];
#undef GRU_STEP
#undef WIHB
#undef MFMA16
}

extern "C" void kernel_launch(void* const* d_in, const int* in_sizes, int n_in,
                              void* d_out, int out_size, void* d_ws, size_t ws_size,
                              hipStream_t stream) {
  const float* chars = (const float*)d_in[0];
  const float* Wih   = (const float*)d_in[1];
  const float* Whh   = (const float*)d_in[2];
  const float* bih   = (const float*)d_in[3];
  const float* bhh   = (const float*)d_in[4];

  _Float16* w16 = (_Float16*)d_ws;   // 36864 f16 = 73728 B

  prep_weights<<<96, 256, 0, stream>>>(Wih, Whh, w16);
  gru_d2<<<512, 256, 0, stream>>>(chars, w16, bih, bhh, (float*)d_out);
}